// Round 1
// baseline (512.517 us; speedup 1.0000x reference)
//
#include <hip/hip_runtime.h>

#define D 64
#define KCODES 1024

// Pass 1: e2[k] = ||embedding[k]||^2  (1024 floats into d_ws)
__global__ __launch_bounds__(256) void e2_kernel(const float* __restrict__ emb,
                                                 float* __restrict__ e2) {
    int k = blockIdx.x * 256 + threadIdx.x;          // grid = 4 * 256 = 1024
    const float4* ep = (const float4*)(emb + (size_t)k * D);
    float s0 = 0.f, s1 = 0.f, s2 = 0.f, s3 = 0.f;
#pragma unroll
    for (int i = 0; i < 16; ++i) {
        float4 v = ep[i];
        s0 = fmaf(v.x, v.x, s0);
        s1 = fmaf(v.y, v.y, s1);
        s2 = fmaf(v.z, v.z, s2);
        s3 = fmaf(v.w, v.w, s3);
    }
    e2[k] = (s0 + s1) + (s2 + s3);
}

// Pass 2: per-row argmin over 1024 codes + fused gather/loss/index epilogue.
// One row per thread; row lives in 64 VGPRs; e_k accessed with wave-uniform k
// so the compiler emits scalar (s_load) broadcasts -- no LDS, no per-lane VMEM
// in the hot loop.
__global__ __launch_bounds__(256) void vq_kernel(
    const float* __restrict__ x, const float* __restrict__ emb,
    const float* __restrict__ e2, float* __restrict__ out_q,
    float* __restrict__ out_idx, float* __restrict__ out_loss, int nrows) {
    int row = blockIdx.x * 256 + threadIdx.x;
    if (row >= nrows) return;

    float xr[D];
    const float4* xp = (const float4*)(x + (size_t)row * D);
#pragma unroll
    for (int i = 0; i < 16; ++i) {
        float4 v = xp[i];
        xr[4 * i + 0] = v.x;
        xr[4 * i + 1] = v.y;
        xr[4 * i + 2] = v.z;
        xr[4 * i + 3] = v.w;
    }

    float best = 3.4e38f;
    int bidx = 0;
    for (int k = 0; k < KCODES; ++k) {
        const float* ek = emb + k * D;   // uniform address -> s_load
        float d0 = 0.f, d1 = 0.f, d2 = 0.f, d3 = 0.f;
#pragma unroll
        for (int i = 0; i < 16; ++i) {
            d0 = fmaf(xr[4 * i + 0], ek[4 * i + 0], d0);
            d1 = fmaf(xr[4 * i + 1], ek[4 * i + 1], d1);
            d2 = fmaf(xr[4 * i + 2], ek[4 * i + 2], d2);
            d3 = fmaf(xr[4 * i + 3], ek[4 * i + 3], d3);
        }
        float dot = (d0 + d1) + (d2 + d3);
        float dist = fmaf(-2.0f, dot, e2[k]);   // ||x||^2 omitted: row-constant
        if (dist < best) { best = dist; bidx = k; }  // strict < == first-min (jnp.argmin)
    }

    // Epilogue: gather chosen code, quantized_sg = x + (q - x), loss = s + 0.25*s
    const float4* qp = (const float4*)(emb + (size_t)bidx * D);
    float4* oq = (float4*)(out_q + (size_t)row * D);
    float l0 = 0.f, l1 = 0.f, l2 = 0.f, l3 = 0.f;
#pragma unroll
    for (int i = 0; i < 16; ++i) {
        float4 q = qp[i];
        float a0 = q.x - xr[4 * i + 0];
        float a1 = q.y - xr[4 * i + 1];
        float a2 = q.z - xr[4 * i + 2];
        float a3 = q.w - xr[4 * i + 3];
        l0 = fmaf(a0, a0, l0);
        l1 = fmaf(a1, a1, l1);
        l2 = fmaf(a2, a2, l2);
        l3 = fmaf(a3, a3, l3);
        float4 o;
        o.x = xr[4 * i + 0] + a0;
        o.y = xr[4 * i + 1] + a1;
        o.z = xr[4 * i + 2] + a2;
        o.w = xr[4 * i + 3] + a3;
        oq[i] = o;
    }
    float s = (l0 + l1) + (l2 + l3);
    out_idx[row] = (float)bidx;
    out_loss[row] = s + 0.25f * s;
}

extern "C" void kernel_launch(void* const* d_in, const int* in_sizes, int n_in,
                              void* d_out, int out_size, void* d_ws, size_t ws_size,
                              hipStream_t stream) {
    const float* x = (const float*)d_in[0];     // [B,T,D] = 256*512*64 fp32
    const float* emb = (const float*)d_in[1];   // [K,D] = 1024*64 fp32
    const int nrows = in_sizes[0] / D;          // 131072

    // Output layout (concatenated flat, all fp32):
    //   [0 .. nrows*D)                quantized_sg
    //   [nrows*D .. nrows*D+nrows)    encoding_indices (as float)
    //   [.. +nrows)                   quantization_loss
    float* out_q = (float*)d_out;
    float* out_idx = out_q + (size_t)nrows * D;
    float* out_loss = out_idx + nrows;

    float* e2 = (float*)d_ws;                   // 1024 floats = 4 KB scratch

    e2_kernel<<<KCODES / 256, 256, 0, stream>>>(emb, e2);
    vq_kernel<<<(nrows + 255) / 256, 256, 0, stream>>>(x, emb, e2, out_q, out_idx,
                                                       out_loss, nrows);
}

// Round 2
// 343.736 us; speedup vs baseline: 1.4910x; 1.4910x over previous
//
#include <hip/hip_runtime.h>

#define D 64
#define KCODES 1024
#define NWAVES 4
#define KSPLIT (KCODES / NWAVES)   // 256 codes per wave
#define ROWS_PER_BLOCK 64

// Pass 1: e2[k] = ||embedding[k]||^2  (1024 floats into d_ws)
__global__ __launch_bounds__(256) void e2_kernel(const float* __restrict__ emb,
                                                 float* __restrict__ e2) {
    int k = blockIdx.x * 256 + threadIdx.x;          // grid = 4 * 256 = 1024
    const float4* ep = (const float4*)(emb + (size_t)k * D);
    float s0 = 0.f, s1 = 0.f, s2 = 0.f, s3 = 0.f;
#pragma unroll
    for (int i = 0; i < 16; ++i) {
        float4 v = ep[i];
        s0 = fmaf(v.x, v.x, s0);
        s1 = fmaf(v.y, v.y, s1);
        s2 = fmaf(v.z, v.z, s2);
        s3 = fmaf(v.w, v.w, s3);
    }
    e2[k] = (s0 + s1) + (s2 + s3);
}

// Pass 2: block = 4 waves x 64 lanes. lane -> row (64-row tile per block),
// wave w -> codebook range [w*256, w*256+256). k is wave-uniform (forced via
// readfirstlane) so e_k comes in as scalar s_loads; 4x wave-parallelism hides
// the K$ latency that starved round-1 (VALUBusy 29.5% @ 2 waves/SIMD).
__global__ __launch_bounds__(256) void vq_kernel(
    const float* __restrict__ x, const float* __restrict__ emb,
    const float* __restrict__ e2, float* __restrict__ out_q,
    float* __restrict__ out_idx, float* __restrict__ out_loss, int nrows) {
    __shared__ float l_best[NWAVES][ROWS_PER_BLOCK];
    __shared__ int l_bidx[NWAVES][ROWS_PER_BLOCK];
    __shared__ float l_loss[NWAVES][ROWS_PER_BLOCK];

    const int tid = threadIdx.x;
    const int lane = tid & 63;
    // Force wave-uniformity so the compiler scalarizes all k-dependent loads.
    const int wave = __builtin_amdgcn_readfirstlane(tid >> 6);
    const int row = blockIdx.x * ROWS_PER_BLOCK + lane;
    if (row >= nrows) return;   // never taken (nrows % 64 == 0), keeps it safe

    // Row into 64 VGPRs (each wave loads its own copy -- L1/L2 hot).
    float xr[D];
    const float4* xp = (const float4*)(x + (size_t)row * D);
#pragma unroll
    for (int i = 0; i < 16; ++i) {
        float4 v = xp[i];
        xr[4 * i + 0] = v.x;
        xr[4 * i + 1] = v.y;
        xr[4 * i + 2] = v.z;
        xr[4 * i + 3] = v.w;
    }

    float best = 3.4e38f;
    int bidx = 0;
    const int k0 = wave * KSPLIT;
    for (int kk = 0; kk < KSPLIT; ++kk) {
        const int k = k0 + kk;
        const float* ek = emb + (size_t)k * D;   // uniform address -> s_load
        float d0 = 0.f, d1 = 0.f, d2 = 0.f, d3 = 0.f;
#pragma unroll
        for (int i = 0; i < 16; ++i) {
            d0 = fmaf(xr[4 * i + 0], ek[4 * i + 0], d0);
            d1 = fmaf(xr[4 * i + 1], ek[4 * i + 1], d1);
            d2 = fmaf(xr[4 * i + 2], ek[4 * i + 2], d2);
            d3 = fmaf(xr[4 * i + 3], ek[4 * i + 3], d3);
        }
        float dot = (d0 + d1) + (d2 + d3);
        float dist = fmaf(-2.0f, dot, e2[k]);   // ||x||^2 omitted: row-constant
        if (dist < best) { best = dist; bidx = k; }  // strict < == first-min
    }
    l_best[wave][lane] = best;
    l_bidx[wave][lane] = bidx;
    __syncthreads();

    // Cross-wave merge (all waves compute it; identical result). Ascending-w
    // order + strict-< tie-break == global first-min (jnp.argmin semantics).
    float bd = l_best[0][lane];
    int bi = l_bidx[0][lane];
#pragma unroll
    for (int w = 1; w < NWAVES; ++w) {
        float d = l_best[w][lane];
        int i2 = l_bidx[w][lane];
        bool take = (d < bd) || (d == bd && i2 < bi);
        bd = take ? d : bd;
        bi = take ? i2 : bi;
    }

    // Epilogue: wave w handles elements [w*16, w*16+16) of its lane's row.
    // Reload x quarter from global (L2-hot) instead of runtime-indexing xr[]
    // (which would force scratch spills).
    const float4* qp = (const float4*)(emb + (size_t)bi * D + wave * 16);
    const float4* xq = (const float4*)(x + (size_t)row * D + wave * 16);
    float4* oq = (float4*)(out_q + (size_t)row * D + wave * 16);
    float l0 = 0.f, l1 = 0.f, l2 = 0.f, l3 = 0.f;
#pragma unroll
    for (int i = 0; i < 4; ++i) {
        float4 q = qp[i];
        float4 xv = xq[i];
        float a0 = q.x - xv.x;
        float a1 = q.y - xv.y;
        float a2 = q.z - xv.z;
        float a3 = q.w - xv.w;
        l0 = fmaf(a0, a0, l0);
        l1 = fmaf(a1, a1, l1);
        l2 = fmaf(a2, a2, l2);
        l3 = fmaf(a3, a3, l3);
        float4 o;   // x + (q - x), matching the reference's fp32 rounding
        o.x = xv.x + a0;
        o.y = xv.y + a1;
        o.z = xv.z + a2;
        o.w = xv.w + a3;
        oq[i] = o;
    }
    l_loss[wave][lane] = (l0 + l1) + (l2 + l3);
    __syncthreads();

    if (wave == 0) {
        float s = (l_loss[0][lane] + l_loss[1][lane]) +
                  (l_loss[2][lane] + l_loss[3][lane]);
        out_idx[row] = (float)bi;
        out_loss[row] = s + 0.25f * s;
    }
}

extern "C" void kernel_launch(void* const* d_in, const int* in_sizes, int n_in,
                              void* d_out, int out_size, void* d_ws, size_t ws_size,
                              hipStream_t stream) {
    const float* x = (const float*)d_in[0];     // [B,T,D] = 256*512*64 fp32
    const float* emb = (const float*)d_in[1];   // [K,D] = 1024*64 fp32
    const int nrows = in_sizes[0] / D;          // 131072

    float* out_q = (float*)d_out;
    float* out_idx = out_q + (size_t)nrows * D;
    float* out_loss = out_idx + nrows;

    float* e2 = (float*)d_ws;                   // 1024 floats = 4 KB scratch

    e2_kernel<<<KCODES / 256, 256, 0, stream>>>(emb, e2);
    vq_kernel<<<nrows / ROWS_PER_BLOCK, 256, 0, stream>>>(x, emb, e2, out_q,
                                                          out_idx, out_loss,
                                                          nrows);
}

// Round 3
// 193.547 us; speedup vs baseline: 2.6480x; 1.7760x over previous
//
#include <hip/hip_runtime.h>
#include <hip/hip_bf16.h>

#define D 64
#define KCODES 1024
#define MARGIN 0.25f     // >=10x the worst-case |approx - exact| distance error
#define FLAG_CAP 8192

typedef __attribute__((ext_vector_type(8))) short bf16x8;
typedef __attribute__((ext_vector_type(4))) float f32x4;

__device__ inline unsigned short f2bf(float f) {
    union { __hip_bfloat16 h; unsigned short s; } cv;
    cv.h = __float2bfloat16(f);
    return cv.s;
}
__device__ inline float bf2f(unsigned short v) {
    union { unsigned short s; __hip_bfloat16 h; } cv;
    cv.s = v;
    return __bfloat162float(cv.h);
}

// k0: e2[k] = ||e_k||^2 (exact round-2 arithmetic), split emb into bf16 hi/lo,
// zero the rescore counter. grid = 1024*64/256 = 256 blocks.
__global__ __launch_bounds__(256) void prep_kernel(
    const float* __restrict__ emb, float* __restrict__ e2,
    unsigned short* __restrict__ ehi, unsigned short* __restrict__ elo,
    unsigned int* __restrict__ counter) {
    int t = blockIdx.x * 256 + threadIdx.x;
    if (t == 0) *counter = 0u;
    if (t < KCODES) {
        const float4* ep = (const float4*)(emb + (size_t)t * D);
        float s0 = 0.f, s1 = 0.f, s2 = 0.f, s3 = 0.f;
#pragma unroll
        for (int i = 0; i < 16; ++i) {
            float4 v = ep[i];
            s0 = fmaf(v.x, v.x, s0);
            s1 = fmaf(v.y, v.y, s1);
            s2 = fmaf(v.z, v.z, s2);
            s3 = fmaf(v.w, v.w, s3);
        }
        e2[t] = (s0 + s1) + (s2 + s3);
    }
    float v = emb[t];
    unsigned short h = f2bf(v);
    ehi[t] = h;
    elo[t] = f2bf(v - bf2f(h));   // v - bf2f(h) is exact (Sterbenz)
}

// k1: MFMA distance argmin. Block = 4 waves x 64 rows = 256 rows.
// Wave: 4 rowsets x 16 rows; loops 64 code-tiles of 16 codes; per tile
// 4 rowsets x 6 mfma_f32_16x16x32_bf16 (3 split terms x 2 K-chunks).
// A layout: A[m=lane&15][k=quad*8+j]; B symmetric (codes row-major = B^T);
// C/D: col(code)=lane&15, row=(lane>>4)*4+reg  [guide-verified m89/m91].
__global__ __launch_bounds__(256) void vq_mfma_kernel(
    const float* __restrict__ x, const float* __restrict__ emb,
    const float* __restrict__ e2, const unsigned short* __restrict__ ehi,
    const unsigned short* __restrict__ elo, float* __restrict__ out_q,
    float* __restrict__ out_idx, float* __restrict__ out_loss,
    unsigned int* __restrict__ counter, int* __restrict__ flaglist) {
    __shared__ int s_bi[256];
    const int tid = threadIdx.x;
    const int lane = tid & 63;
    const int wave = __builtin_amdgcn_readfirstlane(tid >> 6);
    const int quad = lane >> 4;
    const int l15 = lane & 15;
    const int rowBase = blockIdx.x * 256 + wave * 64;

    // A fragments: x rows split into bf16 hi/lo, held in VGPRs for the whole
    // codebook sweep (4 rowsets x 2 kchunks x (hi+lo) = 64 VGPRs).
    bf16x8 ah[4][2], al[4][2];
#pragma unroll
    for (int rs = 0; rs < 4; ++rs) {
        const float* xr = x + (size_t)(rowBase + rs * 16 + l15) * D;
#pragma unroll
        for (int c = 0; c < 2; ++c) {
            const float4* p = (const float4*)(xr + c * 32 + quad * 8);
            float4 f0 = p[0], f1 = p[1];
            float f[8] = {f0.x, f0.y, f0.z, f0.w, f1.x, f1.y, f1.z, f1.w};
            bf16x8 h, l;
#pragma unroll
            for (int j = 0; j < 8; ++j) {
                unsigned short hu = f2bf(f[j]);
                h[j] = (short)hu;
                l[j] = (short)f2bf(f[j] - bf2f(hu));
            }
            ah[rs][c] = h;
            al[rs][c] = l;
        }
    }

    float m1[4][4], m2[4][4];
    int i1[4][4];
#pragma unroll
    for (int rs = 0; rs < 4; ++rs)
#pragma unroll
        for (int r = 0; r < 4; ++r) {
            m1[rs][r] = 3.4e38f;
            m2[rs][r] = 3.4e38f;
            i1[rs][r] = 0;
        }

    for (int t = 0; t < 64; ++t) {
        const int code = t * 16 + l15;
        const float e2v = e2[code];
        const unsigned short* hb = ehi + (size_t)code * D + quad * 8;
        const unsigned short* lb = elo + (size_t)code * D + quad * 8;
        bf16x8 bh0 = *(const bf16x8*)(hb);
        bf16x8 bh1 = *(const bf16x8*)(hb + 32);
        bf16x8 bl0 = *(const bf16x8*)(lb);
        bf16x8 bl1 = *(const bf16x8*)(lb + 32);
#pragma unroll
        for (int rs = 0; rs < 4; ++rs) {
            f32x4 acc = {0.f, 0.f, 0.f, 0.f};
            acc = __builtin_amdgcn_mfma_f32_16x16x32_bf16(ah[rs][0], bh0, acc, 0, 0, 0);
            acc = __builtin_amdgcn_mfma_f32_16x16x32_bf16(ah[rs][0], bl0, acc, 0, 0, 0);
            acc = __builtin_amdgcn_mfma_f32_16x16x32_bf16(al[rs][0], bh0, acc, 0, 0, 0);
            acc = __builtin_amdgcn_mfma_f32_16x16x32_bf16(ah[rs][1], bh1, acc, 0, 0, 0);
            acc = __builtin_amdgcn_mfma_f32_16x16x32_bf16(ah[rs][1], bl1, acc, 0, 0, 0);
            acc = __builtin_amdgcn_mfma_f32_16x16x32_bf16(al[rs][1], bh1, acc, 0, 0, 0);
#pragma unroll
            for (int r = 0; r < 4; ++r) {
                float v = fmaf(-2.0f, acc[r], e2v);
                if (v < m1[rs][r]) {           // ascending t per lane-slice
                    m2[rs][r] = m1[rs][r];
                    m1[rs][r] = v;
                    i1[rs][r] = code;
                } else {
                    m2[rs][r] = fminf(m2[rs][r], v);
                }
            }
        }
    }

    // Cross-lane merge over the 16 code-lanes (same quad => same rows).
#pragma unroll
    for (int rs = 0; rs < 4; ++rs)
#pragma unroll
        for (int r = 0; r < 4; ++r) {
            float v1 = m1[rs][r], v2 = m2[rs][r];
            int ix = i1[rs][r];
#pragma unroll
            for (int mask = 1; mask < 16; mask <<= 1) {
                float o1 = __shfl_xor(v1, mask);
                int oi = __shfl_xor(ix, mask);
                float o2 = __shfl_xor(v2, mask);
                v2 = fminf(fminf(v2, o2), fmaxf(v1, o1));  // union 2nd-min
                bool take = (o1 < v1) || (o1 == v1 && oi < ix);
                v1 = take ? o1 : v1;
                ix = take ? oi : ix;
            }
            m1[rs][r] = v1;
            m2[rs][r] = v2;
            i1[rs][r] = ix;
        }

    if (l15 == 0) {   // lanes 0,16,32,48: writer for rows quad*4+r of each rowset
#pragma unroll
        for (int rs = 0; rs < 4; ++rs)
#pragma unroll
            for (int r = 0; r < 4; ++r) {
                int lrow = wave * 64 + rs * 16 + quad * 4 + r;
                s_bi[lrow] = i1[rs][r];
                if (m2[rs][r] - m1[rs][r] < MARGIN) {
                    unsigned int slot = atomicAdd(counter, 1u);
                    if (slot < FLAG_CAP) flaglist[slot] = blockIdx.x * 256 + lrow;
                }
            }
    }
    __syncthreads();

    // Fused epilogue (round-2-proven arithmetic): one row per thread.
    {
        const int row = blockIdx.x * 256 + tid;
        const int bi = s_bi[tid];
        const float4* qp = (const float4*)(emb + (size_t)bi * D);
        const float4* xp = (const float4*)(x + (size_t)row * D);
        float4* oq = (float4*)(out_q + (size_t)row * D);
        float l0 = 0.f, l1 = 0.f, l2 = 0.f, l3 = 0.f;
#pragma unroll
        for (int i = 0; i < 16; ++i) {
            float4 q = qp[i];
            float4 xv = xp[i];
            float a0 = q.x - xv.x, a1 = q.y - xv.y, a2 = q.z - xv.z, a3 = q.w - xv.w;
            l0 = fmaf(a0, a0, l0);
            l1 = fmaf(a1, a1, l1);
            l2 = fmaf(a2, a2, l2);
            l3 = fmaf(a3, a3, l3);
            float4 o;
            o.x = xv.x + a0;
            o.y = xv.y + a1;
            o.z = xv.z + a2;
            o.w = xv.w + a3;
            oq[i] = o;
        }
        float s = (l0 + l1) + (l2 + l3);
        out_idx[row] = (float)bi;
        out_loss[row] = s + 0.25f * s;
    }
}

// k2: exact fp32 rescore of flagged rows (round-2 formula, proven absmax=0).
// One block per flagged row, grid-stride.
__global__ __launch_bounds__(256) void rescore_kernel(
    const float* __restrict__ x, const float* __restrict__ emb,
    const float* __restrict__ e2, float* __restrict__ out_q,
    float* __restrict__ out_idx, float* __restrict__ out_loss,
    const unsigned int* __restrict__ counter, const int* __restrict__ flaglist) {
    __shared__ float s_d[256];
    __shared__ int s_i[256];
    __shared__ float s_a[D];
    unsigned int n = *counter;
    if (n > FLAG_CAP) n = FLAG_CAP;
    const int tid = threadIdx.x;
    for (unsigned int f = blockIdx.x; f < n; f += gridDim.x) {
        const int row = flaglist[f];
        const float* xr = x + (size_t)row * D;
        float xv[D];
        const float4* xp = (const float4*)xr;
#pragma unroll
        for (int i = 0; i < 16; ++i) {
            float4 v = xp[i];
            xv[4 * i + 0] = v.x;
            xv[4 * i + 1] = v.y;
            xv[4 * i + 2] = v.z;
            xv[4 * i + 3] = v.w;
        }
        float bd = 3.4e38f;
        int bi = 0;
        for (int kk = 0; kk < 4; ++kk) {
            const int k = tid + kk * 256;   // ascending per thread
            const float* ek = emb + (size_t)k * D;
            float d0 = 0.f, d1 = 0.f, d2 = 0.f, d3 = 0.f;
#pragma unroll
            for (int i = 0; i < 16; ++i) {
                d0 = fmaf(xv[4 * i + 0], ek[4 * i + 0], d0);
                d1 = fmaf(xv[4 * i + 1], ek[4 * i + 1], d1);
                d2 = fmaf(xv[4 * i + 2], ek[4 * i + 2], d2);
                d3 = fmaf(xv[4 * i + 3], ek[4 * i + 3], d3);
            }
            float dist = fmaf(-2.0f, (d0 + d1) + (d2 + d3), e2[k]);
            if (dist < bd) { bd = dist; bi = k; }
        }
        s_d[tid] = bd;
        s_i[tid] = bi;
        __syncthreads();
        for (int s = 128; s > 0; s >>= 1) {
            if (tid < s) {
                float od = s_d[tid + s];
                int oi = s_i[tid + s];
                if (od < s_d[tid] || (od == s_d[tid] && oi < s_i[tid])) {
                    s_d[tid] = od;
                    s_i[tid] = oi;
                }
            }
            __syncthreads();
        }
        const int fbi = s_i[0];
        if (tid < D) {
            float xe = xr[tid];
            float a = emb[(size_t)fbi * D + tid] - xe;
            out_q[(size_t)row * D + tid] = xe + a;
            s_a[tid] = a * a;
        }
        __syncthreads();
        if (tid == 0) {
            float l0 = 0.f, l1 = 0.f, l2 = 0.f, l3 = 0.f;
            for (int i = 0; i < 16; ++i) {
                l0 += s_a[4 * i + 0];
                l1 += s_a[4 * i + 1];
                l2 += s_a[4 * i + 2];
                l3 += s_a[4 * i + 3];
            }
            float s = (l0 + l1) + (l2 + l3);
            out_loss[row] = s + 0.25f * s;
            out_idx[row] = (float)fbi;
        }
        __syncthreads();
    }
}

extern "C" void kernel_launch(void* const* d_in, const int* in_sizes, int n_in,
                              void* d_out, int out_size, void* d_ws, size_t ws_size,
                              hipStream_t stream) {
    const float* x = (const float*)d_in[0];     // [B,T,D] fp32
    const float* emb = (const float*)d_in[1];   // [K,D] fp32
    const int nrows = in_sizes[0] / D;          // 131072

    float* out_q = (float*)d_out;
    float* out_idx = out_q + (size_t)nrows * D;
    float* out_loss = out_idx + nrows;

    // ws layout: e2 (4KB) | emb_hi (128KB) | emb_lo (128KB) | counter | list
    char* ws = (char*)d_ws;
    float* e2 = (float*)ws;
    unsigned short* ehi = (unsigned short*)(ws + 4096);
    unsigned short* elo = (unsigned short*)(ws + 4096 + 131072);
    unsigned int* counter = (unsigned int*)(ws + 4096 + 2 * 131072);
    int* flaglist = (int*)(ws + 4096 + 2 * 131072 + 64);

    prep_kernel<<<(KCODES * D) / 256, 256, 0, stream>>>(emb, e2, ehi, elo, counter);
    vq_mfma_kernel<<<nrows / 256, 256, 0, stream>>>(x, emb, e2, ehi, elo, out_q,
                                                    out_idx, out_loss, counter,
                                                    flaglist);
    rescore_kernel<<<256, 256, 0, stream>>>(x, emb, e2, out_q, out_idx, out_loss,
                                            counter, flaglist);
}